// Round 12
// baseline (285.321 us; speedup 1.0000x reference)
//
#include <hip/hip_runtime.h>
#include <hip/hip_bf16.h>

typedef __bf16 bf16_t;
typedef float f32x4 __attribute__((ext_vector_type(4)));
typedef bf16_t bf16x8 __attribute__((ext_vector_type(8)));
typedef bf16_t bf16x4 __attribute__((ext_vector_type(4)));

#define MFMA16(a, b, c) __builtin_amdgcn_mfma_f32_16x16x32_bf16(a, b, c, 0, 0, 0)

// Q pre-scale: 1/sqrt(64) * log2(e), so softmax uses exp2
#define QSCALE 0.18033688011112042f

__device__ __forceinline__ void gl_lds16(const bf16_t* g, bf16_t* l) {
    __builtin_amdgcn_global_load_lds(
        (const __attribute__((address_space(1))) unsigned int*)g,
        (__attribute__((address_space(3))) unsigned int*)l, 16, 0, 0);
}

// Raw v_exp_f32 (libm exp2f adds denorm-fixup VALU; inputs are either
// |s| < ~50 or the -3e38 mask, for which v_exp correctly returns 0).
__device__ __forceinline__ float fexp2(float x) {
    float y;
    asm("v_exp_f32 %0, %1" : "=v"(y) : "v"(x));
    return y;
}

// ---------------------------------------------------------------------------
// Merged prep: blocks [0,6144) convert x fp32->bf16; [6144,7872) transpose
// Wqkv; [7872,8448) transpose Wo.
// ---------------------------------------------------------------------------
__device__ __forceinline__ void conv_t_body(const float* __restrict__ in,
                                            bf16_t* __restrict__ out,
                                            int R, int C, int bx, int by,
                                            float (*t)[33]) {
    const int tx = threadIdx.x & 31;
    const int ty = threadIdx.x >> 5;
#pragma unroll
    for (int i = 0; i < 4; i++)
        t[ty + i * 8][tx] = in[(size_t)(by + ty + i * 8) * C + bx + tx];
    __syncthreads();
#pragma unroll
    for (int i = 0; i < 4; i++)
        out[(size_t)(bx + ty + i * 8) * R + by + tx] = (bf16_t)t[tx][ty + i * 8];
}

__global__ __launch_bounds__(256) void prep_k(
    const float* __restrict__ x,    bf16_t* __restrict__ xb,
    const float* __restrict__ Wqkv, bf16_t* __restrict__ Wt,
    const float* __restrict__ Wo,   bf16_t* __restrict__ Wot)
{
    __shared__ float t[32][33];
    const int blk = blockIdx.x;
    if (blk < 6144) {
        const int i = (blk * 256 + threadIdx.x) * 4;
        float4 v = *(const float4*)(x + i);
        bf16x4 o = { (bf16_t)v.x, (bf16_t)v.y, (bf16_t)v.z, (bf16_t)v.w };
        *(bf16x4*)(xb + i) = o;
    } else if (blk < 7872) {
        const int idx = blk - 6144;
        conv_t_body(Wqkv, Wt, 768, 2304, (idx % 72) * 32, (idx / 72) * 32, t);
    } else {
        const int idx = blk - 7872;
        conv_t_body(Wo, Wot, 768, 768, (idx % 24) * 32, (idx / 24) * 32, t);
    }
}

// ---------------------------------------------------------------------------
// V transpose: Vp [bh][2048][64] -> Vt [bh][64][2048], coalesced both sides.
// (R5 measured: fusing this into gemm0's epilogue costs +12.7us there.)
// ---------------------------------------------------------------------------
__global__ __launch_bounds__(256) void vtrans(const bf16_t* __restrict__ Vp,
                                              bf16_t* __restrict__ Vt) {
    __shared__ __align__(16) bf16_t Ts[64 * 72];
    const int t0 = blockIdx.x * 64;
    const int bh = blockIdx.y;
    const int r  = threadIdx.x >> 2;
    const int cb = (threadIdx.x & 3) * 16;
    const bf16_t* src = Vp + (((size_t)bh * 2048 + t0 + r) << 6) + cb;
    *(bf16x8*)(Ts + r * 72 + cb)     = *(const bf16x8*)(src);
    *(bf16x8*)(Ts + r * 72 + cb + 8) = *(const bf16x8*)(src + 8);
    __syncthreads();
    const int f  = threadIdx.x >> 2;
    const int tb = (threadIdx.x & 3) * 16;
    bf16_t* dst = Vt + (((size_t)bh * 64 + f) << 11) + t0 + tb;
    bf16x8 a, b;
#pragma unroll
    for (int i = 0; i < 8; i++) a[i] = Ts[(tb + i) * 72 + f];
#pragma unroll
    for (int i = 0; i < 8; i++) b[i] = Ts[(tb + 8 + i) * 72 + f];
    *(bf16x8*)(dst)     = a;
    *(bf16x8*)(dst + 8) = b;
}

// ---------------------------------------------------------------------------
// 128x128 bf16 GEMM, BK=32, dbuf, single barrier per K-step, XCD swizzle,
// XOR bank-swizzled LDS tiles.  R3-verified form (47.8us for gemm0).
// ---------------------------------------------------------------------------
template <int EPI>
__global__ __launch_bounds__(256) void gemm_bt(
    const bf16_t* __restrict__ A, const bf16_t* __restrict__ Bt,
    const float* __restrict__ bias,
    void* __restrict__ O0v, bf16_t* __restrict__ O1, bf16_t* __restrict__ O2,
    int M, int N, int K)
{
    __shared__ __align__(16) bf16_t As[2][128 * 32];
    __shared__ __align__(16) bf16_t Bs[2][128 * 32];

    const int tid  = threadIdx.x;
    const int wid  = tid >> 6;
    const int lane = tid & 63;
    const int quad = lane >> 4;
    const int l15  = lane & 15;
    const int wm   = (wid >> 1) * 64;
    const int wn   = (wid & 1) * 64;
    const int qs8  = (quad ^ ((l15 >> 1) & 3)) * 8;   // swizzled colblk (elems)

    const int mtiles = M >> 7;
    const int mtpx   = mtiles >> 3;
    const int bid    = blockIdx.x;
    const int xcd    = bid & 7;
    const int slot   = bid >> 3;
    const int m0     = (xcd * mtpx + (slot % mtpx)) << 7;
    const int n0     = (slot / mtpx) << 7;

    f32x4 acc[4][4];
#pragma unroll
    for (int i = 0; i < 4; i++)
#pragma unroll
        for (int j = 0; j < 4; j++) acc[i][j] = (f32x4){0.f, 0.f, 0.f, 0.f};

    const int srow = tid >> 2;
    const int scol = (((tid & 3) ^ ((srow >> 1) & 3)) ) * 8;   // swizzled source col
    const bf16_t* ag0 = A  + (size_t)(m0 + srow) * K + scol;
    const bf16_t* ag1 = A  + (size_t)(m0 + 64 + srow) * K + scol;
    const bf16_t* bg0 = Bt + (size_t)(n0 + srow) * K + scol;
    const bf16_t* bg1 = Bt + (size_t)(n0 + 64 + srow) * K + scol;

    auto prefetch = [&](int k0, int buf) {
        gl_lds16(ag0 + k0, As[buf] + tid * 8);
        gl_lds16(ag1 + k0, As[buf] + 2048 + tid * 8);
        gl_lds16(bg0 + k0, Bs[buf] + tid * 8);
        gl_lds16(bg1 + k0, Bs[buf] + 2048 + tid * 8);
    };

    const int niter = K >> 5;
    prefetch(0, 0);
    for (int i = 0; i < niter; i++) {
        __syncthreads();
        if (i + 1 < niter) prefetch((i + 1) << 5, (i + 1) & 1);
        const bf16_t* Ap = As[i & 1];
        const bf16_t* Bp = Bs[i & 1];

        bf16x8 af[4], bfr[4];
#pragma unroll
        for (int ii = 0; ii < 4; ii++)
            af[ii] = *(const bf16x8*)(Ap + (wm + ii * 16 + l15) * 32 + qs8);
#pragma unroll
        for (int j = 0; j < 4; j++)
            bfr[j] = *(const bf16x8*)(Bp + (wn + j * 16 + l15) * 32 + qs8);
#pragma unroll
        for (int ii = 0; ii < 4; ii++)
#pragma unroll
            for (int j = 0; j < 4; j++)
                acc[ii][j] = MFMA16(af[ii], bfr[j], acc[ii][j]);
    }

    if (EPI == 0) {
        const int sec = n0 / 768;              // block-uniform
        const float scale = (sec == 0) ? QSCALE : 1.f;
        bf16_t* dst = (sec == 0) ? (bf16_t*)O0v : (sec == 1 ? O1 : O2);
#pragma unroll
        for (int i = 0; i < 4; i++) {
            const int mbase = m0 + wm + i * 16 + quad * 4;
#pragma unroll
            for (int j = 0; j < 4; j++) {
                const int n  = n0 + wn + j * 16 + l15;
                const float bv = bias[n];
                const int d    = n - sec * 768;
                const int h    = d >> 6;
                const int feat = d & 63;
#pragma unroll
                for (int r = 0; r < 4; r++) {
                    const int mm = mbase + r;
                    const int b  = mm >> 11;
                    const int tt = mm & 2047;
                    const int bh = b * 12 + h;
                    dst[(((size_t)bh * 2048 + tt) << 6) + feat] =
                        (bf16_t)((acc[i][j][r] + bv) * scale);
                }
            }
        }
    } else {
#pragma unroll
        for (int i = 0; i < 4; i++) {
            const int mbase = m0 + wm + i * 16 + quad * 4;
#pragma unroll
            for (int j = 0; j < 4; j++) {
                const int n  = n0 + wn + j * 16 + l15;
                const float bv = bias[n];
#pragma unroll
                for (int r = 0; r < 4; r++)
                    ((float*)O0v)[(size_t)(mbase + r) * N + n] = acc[i][j][r] + bv;
            }
        }
    }
}

// ---------------------------------------------------------------------------
// Flash attention, causal — R12: K-direct WITH register double-buffer.
// R11 diagnosis (measured): K global->reg loads issued immediately before the
// barrier exposed full L2 latency every iteration (MfmaUtil 9.7%, VALU 11%,
// occupancy 50% => latency-bound).  The LDS-pipe relief was right; the
// pipelining was lost.
// Fix: kfA/kfB named register buffers, main loop unrolled by 2 (rule #20:
// no runtime-indexed reg arrays).  Tile i+1's kf loads issue right AFTER the
// barrier of iter i, overlapping the whole compute of iter i (~600+cyc); the
// barrier at i+1 (vmcnt(0) for the V-DMA) drains them for free — same hiding
// the old global_load_lds path had.  LDS stays 24KB (Vs+Ps only).
// launch_bounds(256,4): VGPR cap 128 (kfA+kfB=64 + qf 8 + oacc 16 + st 16
// + addr ~= 115, no spill), 4 blocks/CU.  Grid: 1536-block LPT backfill
// (R10-verified); bh keyed on bid%8 for the 6-bh/XCD L2 set (FETCH 19.8MB).
// ---------------------------------------------------------------------------
__global__ __launch_bounds__(256, 4) void attn_k(
    const bf16_t* __restrict__ Q, const bf16_t* __restrict__ Kb,
    const bf16_t* __restrict__ Vt, bf16_t* __restrict__ AO)
{
    __shared__ __align__(16) bf16_t Vs[2 * 4096];   // [buf][kk][feat64][kv32] swz
    __shared__ __align__(16) bf16_t Ps[4 * 1024];   // [wave][16q][64kv] swz

    const int tid  = threadIdx.x;
    const int wid  = tid >> 6;
    const int lane = tid & 63;
    const int quad = lane >> 4;
    const int l15  = lane & 15;
    const int qs8  = (quad ^ ((l15 >> 1) & 3)) * 8;   // swizzled colblk (Vs only)

    // LPT decode: qt descending with bid; bh bijective per 48-block round,
    // XCD digit = bid%8 -> 6-bh L2 set per XCD.
    const int bid = blockIdx.x;
    const int qt  = 31 - (bid / 48);      // 64-row q-tile index, longest first
    const int u   = bid % 48;
    const int bh  = (u & 7) * 6 + (u >> 3);
    const int q0  = qt << 6;

    const bf16_t* Qb  = Q  + ((size_t)bh << 17);
    const bf16_t* Kbh = Kb + ((size_t)bh << 17);
    const bf16_t* Vbh = Vt + ((size_t)bh << 17);

    bf16_t* Pw = Ps + wid * 1024;
    const int swl = l15 & 7;
    bf16_t* pwr[4];
#pragma unroll
    for (int c = 0; c < 4; c++)
        pwr[c] = Pw + l15 * 64 + (((((c << 1) | (quad >> 1))) ^ swl) << 3) + ((quad & 1) << 2);
    const bf16_t* prd[2];
#pragma unroll
    for (int kk = 0; kk < 2; kk++)
        prd[kk] = Pw + l15 * 64 + ((((kk << 2) | quad) ^ swl) << 3);

    const bf16x8 ones = { (bf16_t)1.f, (bf16_t)1.f, (bf16_t)1.f, (bf16_t)1.f,
                          (bf16_t)1.f, (bf16_t)1.f, (bf16_t)1.f, (bf16_t)1.f };

    const int srow = tid >> 2;
    const int scol = (((tid & 3) ^ ((srow >> 1) & 3))) * 8;   // swizzled source col

    // V-only DMA staging
    auto prefetch = [&](int j, int buf) {
        const int kv0 = j * 64;
        bf16_t* vd = Vs + buf * 4096 + tid * 8;
#pragma unroll
        for (int c = 0; c < 2; c++)
            gl_lds16(Vbh + (size_t)srow * 2048 + kv0 + c * 32 + scol, vd + c * 2048);
    };

    // Per-lane K base: row l15 within each 16-row group, features quad*8.
    const bf16_t* kbase = Kbh + l15 * 64 + quad * 8;
    auto kload = [&](bf16x8 (&kf)[4][2], int i) {
        const bf16_t* kp = kbase + (size_t)i * 4096;
#pragma unroll
        for (int c = 0; c < 4; c++)
#pragma unroll
            for (int kk = 0; kk < 2; kk++)
                kf[c][kk] = *(const bf16x8*)(kp + c * 1024 + kk * 32);
    };

    const int b = bh / 12;
    const int h = bh - b * 12;

    const int qg = q0 + wid * 16 + l15;    // this wave's q-row

    bf16x8 qf[2];
    {
        const bf16_t* qp = Qb + ((size_t)qg << 6) + quad * 8;
        qf[0] = *(const bf16x8*)(qp);
        qf[1] = *(const bf16x8*)(qp + 32);
    }

    f32x4 lacc = (f32x4){0.f, 0.f, 0.f, 0.f};
    f32x4 oacc[4];
#pragma unroll
    for (int f = 0; f < 4; f++) oacc[f] = (f32x4){0.f, 0.f, 0.f, 0.f};

    // One KV-tile of work: QK^T from registers, mask, exp2->P, l-sum, PV.
    auto compute = [&](const bf16x8 (&kf)[4][2], const bf16_t* Vp, int i) {
        f32x4 st[4];
        __builtin_amdgcn_s_setprio(1);
#pragma unroll
        for (int c = 0; c < 4; c++) {
            st[c] = (f32x4){0.f, 0.f, 0.f, 0.f};
#pragma unroll
            for (int kk = 0; kk < 2; kk++)
                st[c] = MFMA16(kf[c][kk], qf[kk], st[c]);
        }
        __builtin_amdgcn_s_setprio(0);

        if (i == qt) {                     // causal mask, diagonal tile only
            const int kvb = q0 + quad * 4;
#pragma unroll
            for (int c = 0; c < 4; c++)
#pragma unroll
                for (int r = 0; r < 4; r++)
                    if (kvb + c * 16 + r > qg) st[c][r] = -3e38f;
        }

#pragma unroll
        for (int c = 0; c < 4; c++) {
            bf16x4 pk = { (bf16_t)fexp2(st[c][0]), (bf16_t)fexp2(st[c][1]),
                          (bf16_t)fexp2(st[c][2]), (bf16_t)fexp2(st[c][3]) };
            *(bf16x4*)pwr[c] = pk;
        }

        bf16x8 pb[2];
#pragma unroll
        for (int kk = 0; kk < 2; kk++)
            pb[kk] = *(const bf16x8*)prd[kk];

        __builtin_amdgcn_s_setprio(1);
        lacc = MFMA16(ones, pb[0], lacc);
        lacc = MFMA16(ones, pb[1], lacc);
#pragma unroll
        for (int f = 0; f < 4; f++)
#pragma unroll
            for (int kk = 0; kk < 2; kk++) {
                bf16x8 vf = *(const bf16x8*)(Vp + kk * 2048 + (f * 16 + l15) * 32 + qs8);
                oacc[f] = MFMA16(vf, pb[kk], oacc[f]);
            }
        __builtin_amdgcn_s_setprio(0);
    };

    const int cnt = qt + 1;
    bf16x8 kfA[4][2], kfB[4][2];
    prefetch(0, 0);
    kload(kfA, 0);

    for (int i = 0; i < cnt; i += 2) {
        __syncthreads();                   // drains V(i) DMA + kfA loads
        if (i + 1 < cnt) { prefetch(i + 1, 1); kload(kfB, i + 1); }
        compute(kfA, Vs, i);
        if (i + 1 >= cnt) break;
        __syncthreads();                   // drains V(i+1) DMA + kfB loads
        if (i + 2 < cnt) { prefetch(i + 2, 0); kload(kfA, i + 2); }
        compute(kfB, Vs + 4096, i + 1);
    }

    // Epilogue: normalize in-register (l lane-local) -> bf16 AO
    const float inv = 1.0f / lacc[0];
    bf16_t* dst = AO + ((size_t)(b * 2048 + qg)) * 768 + h * 64 + quad * 4;
#pragma unroll
    for (int f = 0; f < 4; f++) {
        bf16x4 o = { (bf16_t)(oacc[f][0] * inv), (bf16_t)(oacc[f][1] * inv),
                     (bf16_t)(oacc[f][2] * inv), (bf16_t)(oacc[f][3] * inv) };
        *(bf16x4*)(dst + f * 16) = o;
    }
}

// ---------------------------------------------------------------------------
extern "C" void kernel_launch(void* const* d_in, const int* in_sizes, int n_in,
                              void* d_out, int out_size, void* d_ws, size_t ws_size,
                              hipStream_t stream)
{
    const float* x    = (const float*)d_in[0];  // [4,2048,768]
    const float* Wqkv = (const float*)d_in[1];  // [768,2304]
    const float* bqkv = (const float*)d_in[2];  // [2304]
    const float* Wo   = (const float*)d_in[3];  // [768,768]
    const float* bo   = (const float*)d_in[4];  // [768]
    float* out = (float*)d_out;                 // [4,2048,768] fp32

    const size_t per = (size_t)48 * 2048 * 64;  // 6291456 bf16 elems
    bf16_t* Qs  = (bf16_t*)d_ws;                // [bh][t][64], pre-scaled
    bf16_t* Kk  = Qs + per;                     // [bh][t][64]
    bf16_t* Vt  = Kk + per;                     // [bh][64][t]
    bf16_t* AO  = Vt + per;                     // [8192,768] bf16
    bf16_t* xb  = AO + per;                     // [8192,768] bf16
    bf16_t* Wt  = xb + per;                     // [2304,768] = Wqkv^T bf16
    bf16_t* Wot = Wt + (size_t)2304 * 768;      // [768,768]  = Wo^T bf16
    bf16_t* Vpl = (bf16_t*)d_out;               // V plain parked in out

    // 0) merged precision/layout conversions
    prep_k<<<8448, 256, 0, stream>>>(x, xb, Wqkv, Wt, Wo, Wot);

    // 1) QKV projection (coalesced [bh][t][64] for Q, K, V-plain)
    gemm_bt<0><<<18 * 64, 256, 0, stream>>>(
        xb, Wt, bqkv, (void*)Qs, Kk, Vpl, 8192, 2304, 768);
    // 1b) V transpose -> Vt [bh][64][t]
    vtrans<<<dim3(32, 48), 256, 0, stream>>>(Vpl, Vt);
    // 2) causal flash attention -> normalized AO (bf16), LPT backfill grid
    attn_k<<<1536, 256, 0, stream>>>(Qs, Kk, Vt, AO);
    // 3) output projection (fp32 out)
    gemm_bt<1><<<6 * 64, 256, 0, stream>>>(
        AO, Wot, bo, (void*)out, nullptr, nullptr, 8192, 768, 768);
}

// Round 13
// 196.669 us; speedup vs baseline: 1.4508x; 1.4508x over previous
//
#include <hip/hip_runtime.h>
#include <hip/hip_bf16.h>

typedef __bf16 bf16_t;
typedef float f32x4 __attribute__((ext_vector_type(4)));
typedef bf16_t bf16x8 __attribute__((ext_vector_type(8)));
typedef bf16_t bf16x4 __attribute__((ext_vector_type(4)));

#define MFMA16(a, b, c) __builtin_amdgcn_mfma_f32_16x16x32_bf16(a, b, c, 0, 0, 0)

// Q pre-scale: 1/sqrt(64) * log2(e), so softmax uses exp2
#define QSCALE 0.18033688011112042f

__device__ __forceinline__ void gl_lds16(const bf16_t* g, bf16_t* l) {
    __builtin_amdgcn_global_load_lds(
        (const __attribute__((address_space(1))) unsigned int*)g,
        (__attribute__((address_space(3))) unsigned int*)l, 16, 0, 0);
}

// Raw v_exp_f32 (libm exp2f adds denorm-fixup VALU; inputs are either
// |s| < ~50 or the -3e38 mask, for which v_exp correctly returns 0).
__device__ __forceinline__ float fexp2(float x) {
    float y;
    asm("v_exp_f32 %0, %1" : "=v"(y) : "v"(x));
    return y;
}

// ---------------------------------------------------------------------------
// Merged prep: blocks [0,6144) convert x fp32->bf16; [6144,7872) transpose
// Wqkv; [7872,8448) transpose Wo.
// ---------------------------------------------------------------------------
__device__ __forceinline__ void conv_t_body(const float* __restrict__ in,
                                            bf16_t* __restrict__ out,
                                            int R, int C, int bx, int by,
                                            float (*t)[33]) {
    const int tx = threadIdx.x & 31;
    const int ty = threadIdx.x >> 5;
#pragma unroll
    for (int i = 0; i < 4; i++)
        t[ty + i * 8][tx] = in[(size_t)(by + ty + i * 8) * C + bx + tx];
    __syncthreads();
#pragma unroll
    for (int i = 0; i < 4; i++)
        out[(size_t)(bx + ty + i * 8) * R + by + tx] = (bf16_t)t[tx][ty + i * 8];
}

__global__ __launch_bounds__(256) void prep_k(
    const float* __restrict__ x,    bf16_t* __restrict__ xb,
    const float* __restrict__ Wqkv, bf16_t* __restrict__ Wt,
    const float* __restrict__ Wo,   bf16_t* __restrict__ Wot)
{
    __shared__ float t[32][33];
    const int blk = blockIdx.x;
    if (blk < 6144) {
        const int i = (blk * 256 + threadIdx.x) * 4;
        float4 v = *(const float4*)(x + i);
        bf16x4 o = { (bf16_t)v.x, (bf16_t)v.y, (bf16_t)v.z, (bf16_t)v.w };
        *(bf16x4*)(xb + i) = o;
    } else if (blk < 7872) {
        const int idx = blk - 6144;
        conv_t_body(Wqkv, Wt, 768, 2304, (idx % 72) * 32, (idx / 72) * 32, t);
    } else {
        const int idx = blk - 7872;
        conv_t_body(Wo, Wot, 768, 768, (idx % 24) * 32, (idx / 24) * 32, t);
    }
}

// ---------------------------------------------------------------------------
// V transpose: Vp [bh][2048][64] -> Vt [bh][64][2048], coalesced both sides.
// (R5 measured: fusing this into gemm0's epilogue costs +12.7us there.)
// ---------------------------------------------------------------------------
__global__ __launch_bounds__(256) void vtrans(const bf16_t* __restrict__ Vp,
                                              bf16_t* __restrict__ Vt) {
    __shared__ __align__(16) bf16_t Ts[64 * 72];
    const int t0 = blockIdx.x * 64;
    const int bh = blockIdx.y;
    const int r  = threadIdx.x >> 2;
    const int cb = (threadIdx.x & 3) * 16;
    const bf16_t* src = Vp + (((size_t)bh * 2048 + t0 + r) << 6) + cb;
    *(bf16x8*)(Ts + r * 72 + cb)     = *(const bf16x8*)(src);
    *(bf16x8*)(Ts + r * 72 + cb + 8) = *(const bf16x8*)(src + 8);
    __syncthreads();
    const int f  = threadIdx.x >> 2;
    const int tb = (threadIdx.x & 3) * 16;
    bf16_t* dst = Vt + (((size_t)bh * 64 + f) << 11) + t0 + tb;
    bf16x8 a, b;
#pragma unroll
    for (int i = 0; i < 8; i++) a[i] = Ts[(tb + i) * 72 + f];
#pragma unroll
    for (int i = 0; i < 8; i++) b[i] = Ts[(tb + 8 + i) * 72 + f];
    *(bf16x8*)(dst)     = a;
    *(bf16x8*)(dst + 8) = b;
}

// ---------------------------------------------------------------------------
// 128x128 bf16 GEMM, BK=32, dbuf, single barrier per K-step, XCD swizzle,
// XOR bank-swizzled LDS tiles.  R3-verified form (47.8us for gemm0).
// ---------------------------------------------------------------------------
template <int EPI>
__global__ __launch_bounds__(256) void gemm_bt(
    const bf16_t* __restrict__ A, const bf16_t* __restrict__ Bt,
    const float* __restrict__ bias,
    void* __restrict__ O0v, bf16_t* __restrict__ O1, bf16_t* __restrict__ O2,
    int M, int N, int K)
{
    __shared__ __align__(16) bf16_t As[2][128 * 32];
    __shared__ __align__(16) bf16_t Bs[2][128 * 32];

    const int tid  = threadIdx.x;
    const int wid  = tid >> 6;
    const int lane = tid & 63;
    const int quad = lane >> 4;
    const int l15  = lane & 15;
    const int wm   = (wid >> 1) * 64;
    const int wn   = (wid & 1) * 64;
    const int qs8  = (quad ^ ((l15 >> 1) & 3)) * 8;   // swizzled colblk (elems)

    const int mtiles = M >> 7;
    const int mtpx   = mtiles >> 3;
    const int bid    = blockIdx.x;
    const int xcd    = bid & 7;
    const int slot   = bid >> 3;
    const int m0     = (xcd * mtpx + (slot % mtpx)) << 7;
    const int n0     = (slot / mtpx) << 7;

    f32x4 acc[4][4];
#pragma unroll
    for (int i = 0; i < 4; i++)
#pragma unroll
        for (int j = 0; j < 4; j++) acc[i][j] = (f32x4){0.f, 0.f, 0.f, 0.f};

    const int srow = tid >> 2;
    const int scol = (((tid & 3) ^ ((srow >> 1) & 3)) ) * 8;   // swizzled source col
    const bf16_t* ag0 = A  + (size_t)(m0 + srow) * K + scol;
    const bf16_t* ag1 = A  + (size_t)(m0 + 64 + srow) * K + scol;
    const bf16_t* bg0 = Bt + (size_t)(n0 + srow) * K + scol;
    const bf16_t* bg1 = Bt + (size_t)(n0 + 64 + srow) * K + scol;

    auto prefetch = [&](int k0, int buf) {
        gl_lds16(ag0 + k0, As[buf] + tid * 8);
        gl_lds16(ag1 + k0, As[buf] + 2048 + tid * 8);
        gl_lds16(bg0 + k0, Bs[buf] + tid * 8);
        gl_lds16(bg1 + k0, Bs[buf] + 2048 + tid * 8);
    };

    const int niter = K >> 5;
    prefetch(0, 0);
    for (int i = 0; i < niter; i++) {
        __syncthreads();
        if (i + 1 < niter) prefetch((i + 1) << 5, (i + 1) & 1);
        const bf16_t* Ap = As[i & 1];
        const bf16_t* Bp = Bs[i & 1];

        bf16x8 af[4], bfr[4];
#pragma unroll
        for (int ii = 0; ii < 4; ii++)
            af[ii] = *(const bf16x8*)(Ap + (wm + ii * 16 + l15) * 32 + qs8);
#pragma unroll
        for (int j = 0; j < 4; j++)
            bfr[j] = *(const bf16x8*)(Bp + (wn + j * 16 + l15) * 32 + qs8);
#pragma unroll
        for (int ii = 0; ii < 4; ii++)
#pragma unroll
            for (int j = 0; j < 4; j++)
                acc[ii][j] = MFMA16(af[ii], bfr[j], acc[ii][j]);
    }

    if (EPI == 0) {
        const int sec = n0 / 768;              // block-uniform
        const float scale = (sec == 0) ? QSCALE : 1.f;
        bf16_t* dst = (sec == 0) ? (bf16_t*)O0v : (sec == 1 ? O1 : O2);
#pragma unroll
        for (int i = 0; i < 4; i++) {
            const int mbase = m0 + wm + i * 16 + quad * 4;
#pragma unroll
            for (int j = 0; j < 4; j++) {
                const int n  = n0 + wn + j * 16 + l15;
                const float bv = bias[n];
                const int d    = n - sec * 768;
                const int h    = d >> 6;
                const int feat = d & 63;
#pragma unroll
                for (int r = 0; r < 4; r++) {
                    const int mm = mbase + r;
                    const int b  = mm >> 11;
                    const int tt = mm & 2047;
                    const int bh = b * 12 + h;
                    dst[(((size_t)bh * 2048 + tt) << 6) + feat] =
                        (bf16_t)((acc[i][j][r] + bv) * scale);
                }
            }
        }
    } else {
#pragma unroll
        for (int i = 0; i < 4; i++) {
            const int mbase = m0 + wm + i * 16 + quad * 4;
#pragma unroll
            for (int j = 0; j < 4; j++) {
                const int n  = n0 + wn + j * 16 + l15;
                const float bv = bias[n];
#pragma unroll
                for (int r = 0; r < 4; r++)
                    ((float*)O0v)[(size_t)(mbase + r) * N + n] = acc[i][j][r] + bv;
            }
        }
    }
}

// ---------------------------------------------------------------------------
// Flash attention, causal — R13: 2-group body (R3, thrice-refchecked) +
// LPT BACKFILL dispatch (R10-verified) + XCD-bh L2 keying (R10-verified).
// R12 post-mortem: K-direct-to-reg spilled (lambda-referenced arrays ->
// scratch; WRITE_SIZE 12->44MB).  K-direct line closed.
// Mechanism combination: 2-group halves K/V LDS fragment reads per q (the
// R10 wall: LDS pipe ~81% busy); backfill sustains ~2 blocks/CU steady (the
// R3 wall: no-backfill triples collapsed to ~1.4 live blocks, occ 18%).
// LDS deliberately padded to 56KB (Ps stride 3072) -> capacity 2 blocks/CU;
// grid 768 > 512 resident -> 256 queued, LPT order (qt2 descending) keeps
// CUs full until the short tail.  bh = f(bid%8) -> 6-bh set per XCD
// (K+V 3MB, L2-resident; R10 FETCH 19.8MB confirms).
// ---------------------------------------------------------------------------
__global__ __launch_bounds__(256, 2) void attn_k(
    const bf16_t* __restrict__ Q, const bf16_t* __restrict__ Kb,
    const bf16_t* __restrict__ Vt, bf16_t* __restrict__ AO)
{
    __shared__ __align__(16) bf16_t Ks[2 * 4096];   // [buf][kk][kv64][feat32] swz
    __shared__ __align__(16) bf16_t Vs[2 * 4096];   // [buf][kk][feat64][kv32] swz
    __shared__ __align__(16) bf16_t Ps[4 * 3072];   // [wave][grp][16q][64kv] swz
    // 16KB + 16KB + 24KB (1KB/wave pad) = 56KB -> exactly 2 blocks/CU

    const int tid  = threadIdx.x;
    const int wid  = tid >> 6;
    const int lane = tid & 63;
    const int quad = lane >> 4;
    const int l15  = lane & 15;
    const int qs8  = (quad ^ ((l15 >> 1) & 3)) * 8;   // swizzled colblk

    // LPT decode: qt2 descending with bid (longest first, backfill eats the
    // tail); bh keyed on bid%8 -> fixed 6-bh set per XCD.
    const int bid = blockIdx.x;
    const int qt2 = 15 - (bid / 48);      // 128-row q-tile index, 15..0
    const int u   = bid % 48;
    const int bh  = (u & 7) * 6 + (u >> 3);
    const int q0  = qt2 << 7;

    const bf16_t* Qb  = Q  + ((size_t)bh << 17);
    const bf16_t* Kbh = Kb + ((size_t)bh << 17);
    const bf16_t* Vbh = Vt + ((size_t)bh << 17);

    bf16_t* Pw = Ps + wid * 3072;
    const int swl = l15 & 7;
    bf16_t* pwr[2][4];
    const bf16_t* prd[2][2];
#pragma unroll
    for (int g = 0; g < 2; g++) {
#pragma unroll
        for (int c = 0; c < 4; c++)
            pwr[g][c] = Pw + g * 1024 + l15 * 64 +
                        (((((c << 1) | (quad >> 1))) ^ swl) << 3) + ((quad & 1) << 2);
#pragma unroll
        for (int kk = 0; kk < 2; kk++)
            prd[g][kk] = Pw + g * 1024 + l15 * 64 + ((((kk << 2) | quad) ^ swl) << 3);
    }

    const bf16x8 ones = { (bf16_t)1.f, (bf16_t)1.f, (bf16_t)1.f, (bf16_t)1.f,
                          (bf16_t)1.f, (bf16_t)1.f, (bf16_t)1.f, (bf16_t)1.f };

    const int srow = tid >> 2;
    const int scol = (((tid & 3) ^ ((srow >> 1) & 3))) * 8;   // swizzled source col

    auto prefetch = [&](int j, int buf) {
        const int kv0 = j * 64;
        bf16_t* kd = Ks + buf * 4096 + tid * 8;
        bf16_t* vd = Vs + buf * 4096 + tid * 8;
#pragma unroll
        for (int c = 0; c < 2; c++) {
            gl_lds16(Kbh + (size_t)(kv0 + srow) * 64 + c * 32 + scol, kd + c * 2048);
            gl_lds16(Vbh + (size_t)srow * 2048 + kv0 + c * 32 + scol, vd + c * 2048);
        }
    };

    const int b = bh / 12;
    const int h = bh - b * 12;

    const int qg0 = q0 + wid * 16 + l15;   // group0 q-row
    const int qg1 = qg0 + 64;              // group1 q-row

    bf16x8 qf[2][2];
#pragma unroll
    for (int g = 0; g < 2; g++) {
        const bf16_t* qp = Qb + ((size_t)(g ? qg1 : qg0) << 6) + quad * 8;
        qf[g][0] = *(const bf16x8*)(qp);
        qf[g][1] = *(const bf16x8*)(qp + 32);
    }

    f32x4 lacc[2];
    f32x4 oacc[2][4];
#pragma unroll
    for (int g = 0; g < 2; g++) {
        lacc[g] = (f32x4){0.f, 0.f, 0.f, 0.f};
#pragma unroll
        for (int f = 0; f < 4; f++) oacc[g][f] = (f32x4){0.f, 0.f, 0.f, 0.f};
    }

    const int cnt = 2 * qt2 + 2;           // kv tiles needed by group1
    prefetch(0, 0);

    for (int i = 0; i < cnt; i++) {
        __syncthreads();                   // drains prefetch from iter i-1
        if (i + 1 < cnt) prefetch(i + 1, (i + 1) & 1);
        const bf16_t* Kp = Ks + (i & 1) * 4096;
        const bf16_t* Vp = Vs + (i & 1) * 4096;

        // S^T = K Q^T for both q-groups: kf loaded ONCE, used twice.
        f32x4 st[2][4];
        __builtin_amdgcn_s_setprio(1);
#pragma unroll
        for (int c = 0; c < 4; c++) {
            st[0][c] = (f32x4){0.f, 0.f, 0.f, 0.f};
            st[1][c] = (f32x4){0.f, 0.f, 0.f, 0.f};
#pragma unroll
            for (int kk = 0; kk < 2; kk++) {
                bf16x8 kf = *(const bf16x8*)(Kp + kk * 2048 + (c * 16 + l15) * 32 + qs8);
                st[0][c] = MFMA16(kf, qf[0][kk], st[0][c]);
                st[1][c] = MFMA16(kf, qf[1][kk], st[1][c]);
            }
        }
        __builtin_amdgcn_s_setprio(0);

        // Causal masks.  Group0 diag at i==2*qt2; fully masked at i==2*qt2+1
        // (exp -> 0, branch-free).  Group1 diag at i==2*qt2+1.
        const int kvb = i * 64 + quad * 4;
        if (i >= 2 * qt2) {
#pragma unroll
            for (int c = 0; c < 4; c++)
#pragma unroll
                for (int r = 0; r < 4; r++)
                    if (kvb + c * 16 + r > qg0) st[0][c][r] = -3e38f;
            if (i == 2 * qt2 + 1) {
#pragma unroll
                for (int c = 0; c < 4; c++)
#pragma unroll
                    for (int r = 0; r < 4; r++)
                        if (kvb + c * 16 + r > qg1) st[1][c][r] = -3e38f;
            }
        }

        // P^T = exp2(S^T): one b64 LDS write per (g,c)
#pragma unroll
        for (int g = 0; g < 2; g++)
#pragma unroll
            for (int c = 0; c < 4; c++) {
                bf16x4 pk = { (bf16_t)fexp2(st[g][c][0]), (bf16_t)fexp2(st[g][c][1]),
                              (bf16_t)fexp2(st[g][c][2]), (bf16_t)fexp2(st[g][c][3]) };
                *(bf16x4*)pwr[g][c] = pk;
            }

        bf16x8 pb[2][2];
#pragma unroll
        for (int g = 0; g < 2; g++)
#pragma unroll
            for (int kk = 0; kk < 2; kk++)
                pb[g][kk] = *(const bf16x8*)prd[g][kk];

        __builtin_amdgcn_s_setprio(1);
        // l[q] += colsum(P^T): lands at col=l15 (lane-local)
        lacc[0] = MFMA16(ones, pb[0][0], lacc[0]);
        lacc[0] = MFMA16(ones, pb[0][1], lacc[0]);
        lacc[1] = MFMA16(ones, pb[1][0], lacc[1]);
        lacc[1] = MFMA16(ones, pb[1][1], lacc[1]);

        // O^T += V^T P^T for both groups: vf loaded ONCE, used twice.
#pragma unroll
        for (int f = 0; f < 4; f++)
#pragma unroll
            for (int kk = 0; kk < 2; kk++) {
                bf16x8 vf = *(const bf16x8*)(Vp + kk * 2048 + (f * 16 + l15) * 32 + qs8);
                oacc[0][f] = MFMA16(vf, pb[0][kk], oacc[0][f]);
                oacc[1][f] = MFMA16(vf, pb[1][kk], oacc[1][f]);
            }
        __builtin_amdgcn_s_setprio(0);
    }

    // Epilogue: normalize in-register (l lane-local) -> bf16 AO, both groups
#pragma unroll
    for (int g = 0; g < 2; g++) {
        const float inv = 1.0f / lacc[g][0];
        const int qg = g ? qg1 : qg0;
        bf16_t* dst = AO + ((size_t)(b * 2048 + qg)) * 768 + h * 64 + quad * 4;
#pragma unroll
        for (int f = 0; f < 4; f++) {
            bf16x4 o = { (bf16_t)(oacc[g][f][0] * inv), (bf16_t)(oacc[g][f][1] * inv),
                         (bf16_t)(oacc[g][f][2] * inv), (bf16_t)(oacc[g][f][3] * inv) };
            *(bf16x4*)(dst + f * 16) = o;
        }
    }
}

// ---------------------------------------------------------------------------
extern "C" void kernel_launch(void* const* d_in, const int* in_sizes, int n_in,
                              void* d_out, int out_size, void* d_ws, size_t ws_size,
                              hipStream_t stream)
{
    const float* x    = (const float*)d_in[0];  // [4,2048,768]
    const float* Wqkv = (const float*)d_in[1];  // [768,2304]
    const float* bqkv = (const float*)d_in[2];  // [2304]
    const float* Wo   = (const float*)d_in[3];  // [768,768]
    const float* bo   = (const float*)d_in[4];  // [768]
    float* out = (float*)d_out;                 // [4,2048,768] fp32

    const size_t per = (size_t)48 * 2048 * 64;  // 6291456 bf16 elems
    bf16_t* Qs  = (bf16_t*)d_ws;                // [bh][t][64], pre-scaled
    bf16_t* Kk  = Qs + per;                     // [bh][t][64]
    bf16_t* Vt  = Kk + per;                     // [bh][64][t]
    bf16_t* AO  = Vt + per;                     // [8192,768] bf16
    bf16_t* xb  = AO + per;                     // [8192,768] bf16
    bf16_t* Wt  = xb + per;                     // [2304,768] = Wqkv^T bf16
    bf16_t* Wot = Wt + (size_t)2304 * 768;      // [768,768]  = Wo^T bf16
    bf16_t* Vpl = (bf16_t*)d_out;               // V plain parked in out

    // 0) merged precision/layout conversions
    prep_k<<<8448, 256, 0, stream>>>(x, xb, Wqkv, Wt, Wo, Wot);

    // 1) QKV projection (coalesced [bh][t][64] for Q, K, V-plain)
    gemm_bt<0><<<18 * 64, 256, 0, stream>>>(
        xb, Wt, bqkv, (void*)Qs, Kk, Vpl, 8192, 2304, 768);
    // 1b) V transpose -> Vt [bh][64][t]
    vtrans<<<dim3(32, 48), 256, 0, stream>>>(Vpl, Vt);
    // 2) causal flash attention -> normalized AO (bf16), LPT backfill grid
    attn_k<<<768, 256, 0, stream>>>(Qs, Kk, Vt, AO);
    // 3) output projection (fp32 out)
    gemm_bt<1><<<6 * 64, 256, 0, stream>>>(
        AO, Wot, bo, (void*)out, nullptr, nullptr, 8192, 768, 768);
}

// Round 15
// 192.845 us; speedup vs baseline: 1.4795x; 1.0198x over previous
//
#include <hip/hip_runtime.h>
#include <hip/hip_bf16.h>

typedef __bf16 bf16_t;
typedef float f32x4 __attribute__((ext_vector_type(4)));
typedef bf16_t bf16x8 __attribute__((ext_vector_type(8)));
typedef bf16_t bf16x4 __attribute__((ext_vector_type(4)));

#define MFMA16(a, b, c) __builtin_amdgcn_mfma_f32_16x16x32_bf16(a, b, c, 0, 0, 0)

// Q pre-scale: 1/sqrt(64) * log2(e), so softmax uses exp2
#define QSCALE 0.18033688011112042f

__device__ __forceinline__ void gl_lds16(const bf16_t* g, bf16_t* l) {
    __builtin_amdgcn_global_load_lds(
        (const __attribute__((address_space(1))) unsigned int*)g,
        (__attribute__((address_space(3))) unsigned int*)l, 16, 0, 0);
}

// Raw v_exp_f32 (libm exp2f adds denorm-fixup VALU; inputs are either
// |s| < ~50 or the -3e38 mask, for which v_exp correctly returns 0).
__device__ __forceinline__ float fexp2(float x) {
    float y;
    asm("v_exp_f32 %0, %1" : "=v"(y) : "v"(x));
    return y;
}

// ---------------------------------------------------------------------------
// Merged prep: blocks [0,6144) convert x fp32->bf16; [6144,7872) transpose
// Wqkv; [7872,8448) transpose Wo.
// ---------------------------------------------------------------------------
__device__ __forceinline__ void conv_t_body(const float* __restrict__ in,
                                            bf16_t* __restrict__ out,
                                            int R, int C, int bx, int by,
                                            float (*t)[33]) {
    const int tx = threadIdx.x & 31;
    const int ty = threadIdx.x >> 5;
#pragma unroll
    for (int i = 0; i < 4; i++)
        t[ty + i * 8][tx] = in[(size_t)(by + ty + i * 8) * C + bx + tx];
    __syncthreads();
#pragma unroll
    for (int i = 0; i < 4; i++)
        out[(size_t)(bx + ty + i * 8) * R + by + tx] = (bf16_t)t[tx][ty + i * 8];
}

__global__ __launch_bounds__(256) void prep_k(
    const float* __restrict__ x,    bf16_t* __restrict__ xb,
    const float* __restrict__ Wqkv, bf16_t* __restrict__ Wt,
    const float* __restrict__ Wo,   bf16_t* __restrict__ Wot)
{
    __shared__ float t[32][33];
    const int blk = blockIdx.x;
    if (blk < 6144) {
        const int i = (blk * 256 + threadIdx.x) * 4;
        float4 v = *(const float4*)(x + i);
        bf16x4 o = { (bf16_t)v.x, (bf16_t)v.y, (bf16_t)v.z, (bf16_t)v.w };
        *(bf16x4*)(xb + i) = o;
    } else if (blk < 7872) {
        const int idx = blk - 6144;
        conv_t_body(Wqkv, Wt, 768, 2304, (idx % 72) * 32, (idx / 72) * 32, t);
    } else {
        const int idx = blk - 7872;
        conv_t_body(Wo, Wot, 768, 768, (idx % 24) * 32, (idx / 24) * 32, t);
    }
}

// ---------------------------------------------------------------------------
// V transpose: Vp [bh][2048][64] -> Vt [bh][64][2048], coalesced both sides.
// (R5 measured: fusing this into gemm0's epilogue costs +12.7us there.)
// ---------------------------------------------------------------------------
__global__ __launch_bounds__(256) void vtrans(const bf16_t* __restrict__ Vp,
                                              bf16_t* __restrict__ Vt) {
    __shared__ __align__(16) bf16_t Ts[64 * 72];
    const int t0 = blockIdx.x * 64;
    const int bh = blockIdx.y;
    const int r  = threadIdx.x >> 2;
    const int cb = (threadIdx.x & 3) * 16;
    const bf16_t* src = Vp + (((size_t)bh * 2048 + t0 + r) << 6) + cb;
    *(bf16x8*)(Ts + r * 72 + cb)     = *(const bf16x8*)(src);
    *(bf16x8*)(Ts + r * 72 + cb + 8) = *(const bf16x8*)(src + 8);
    __syncthreads();
    const int f  = threadIdx.x >> 2;
    const int tb = (threadIdx.x & 3) * 16;
    bf16_t* dst = Vt + (((size_t)bh * 64 + f) << 11) + t0 + tb;
    bf16x8 a, b;
#pragma unroll
    for (int i = 0; i < 8; i++) a[i] = Ts[(tb + i) * 72 + f];
#pragma unroll
    for (int i = 0; i < 8; i++) b[i] = Ts[(tb + 8 + i) * 72 + f];
    *(bf16x8*)(dst)     = a;
    *(bf16x8*)(dst + 8) = b;
}

// ---------------------------------------------------------------------------
// 128xBN bf16 GEMM, BK=32, dbuf, single barrier per K-step, XCD swizzle,
// XOR bank-swizzled LDS tiles.  BN=128: R3-verified form (47.8us gemm0).
// R14: BN=64 variant for gemm1 — 384 blocks @128x128 on 256 CUs was a 2:1
// round imbalance (75% efficiency); 128x64 -> 768 blocks = exactly 3/CU,
// all co-resident (24KB LDS).  BN=128 instantiation is compile-time
// identical to R13's gemm0.  (Desk-verified: bijective (m0,n0) cover,
// B-staging rows 0..63, wave layout 128x64 exact.)
// ---------------------------------------------------------------------------
template <int EPI, int BN>
__global__ __launch_bounds__(256) void gemm_bt(
    const bf16_t* __restrict__ A, const bf16_t* __restrict__ Bt,
    const float* __restrict__ bias,
    void* __restrict__ O0v, bf16_t* __restrict__ O1, bf16_t* __restrict__ O2,
    int M, int N, int K)
{
    constexpr int NJ = BN / 32;            // N-frags per wave
    __shared__ __align__(16) bf16_t As[2][128 * 32];
    __shared__ __align__(16) bf16_t Bs[2][BN * 32];

    const int tid  = threadIdx.x;
    const int wid  = tid >> 6;
    const int lane = tid & 63;
    const int quad = lane >> 4;
    const int l15  = lane & 15;
    const int wm   = (wid >> 1) * 64;
    const int wn   = (wid & 1) * (BN / 2);
    const int qs8  = (quad ^ ((l15 >> 1) & 3)) * 8;   // swizzled colblk (elems)

    const int mtiles = M >> 7;
    const int mtpx   = mtiles >> 3;
    const int bid    = blockIdx.x;
    const int xcd    = bid & 7;
    const int slot   = bid >> 3;
    const int m0     = (xcd * mtpx + (slot % mtpx)) << 7;
    const int n0     = (slot / mtpx) * BN;

    f32x4 acc[4][NJ];
#pragma unroll
    for (int i = 0; i < 4; i++)
#pragma unroll
        for (int j = 0; j < NJ; j++) acc[i][j] = (f32x4){0.f, 0.f, 0.f, 0.f};

    const int srow = tid >> 2;
    const int scol = (((tid & 3) ^ ((srow >> 1) & 3)) ) * 8;   // swizzled source col
    const bf16_t* ag0 = A  + (size_t)(m0 + srow) * K + scol;
    const bf16_t* ag1 = A  + (size_t)(m0 + 64 + srow) * K + scol;
    const bf16_t* bg0 = Bt + (size_t)(n0 + srow) * K + scol;
    const bf16_t* bg1 = Bt + (size_t)(n0 + 64 + srow) * K + scol;  // BN==128 only

    auto prefetch = [&](int k0, int buf) {
        gl_lds16(ag0 + k0, As[buf] + tid * 8);
        gl_lds16(ag1 + k0, As[buf] + 2048 + tid * 8);
        gl_lds16(bg0 + k0, Bs[buf] + tid * 8);
        if constexpr (BN == 128)
            gl_lds16(bg1 + k0, Bs[buf] + 2048 + tid * 8);
    };

    const int niter = K >> 5;
    prefetch(0, 0);
    for (int i = 0; i < niter; i++) {
        __syncthreads();
        if (i + 1 < niter) prefetch((i + 1) << 5, (i + 1) & 1);
        const bf16_t* Ap = As[i & 1];
        const bf16_t* Bp = Bs[i & 1];

        bf16x8 af[4], bfr[NJ];
#pragma unroll
        for (int ii = 0; ii < 4; ii++)
            af[ii] = *(const bf16x8*)(Ap + (wm + ii * 16 + l15) * 32 + qs8);
#pragma unroll
        for (int j = 0; j < NJ; j++)
            bfr[j] = *(const bf16x8*)(Bp + (wn + j * 16 + l15) * 32 + qs8);
#pragma unroll
        for (int ii = 0; ii < 4; ii++)
#pragma unroll
            for (int j = 0; j < NJ; j++)
                acc[ii][j] = MFMA16(af[ii], bfr[j], acc[ii][j]);
    }

    if (EPI == 0) {
        const int sec = n0 / 768;              // block-uniform
        const float scale = (sec == 0) ? QSCALE : 1.f;
        bf16_t* dst = (sec == 0) ? (bf16_t*)O0v : (sec == 1 ? O1 : O2);
#pragma unroll
        for (int i = 0; i < 4; i++) {
            const int mbase = m0 + wm + i * 16 + quad * 4;
#pragma unroll
            for (int j = 0; j < NJ; j++) {
                const int n  = n0 + wn + j * 16 + l15;
                const float bv = bias[n];
                const int d    = n - sec * 768;
                const int h    = d >> 6;
                const int feat = d & 63;
#pragma unroll
                for (int r = 0; r < 4; r++) {
                    const int mm = mbase + r;
                    const int b  = mm >> 11;
                    const int tt = mm & 2047;
                    const int bh = b * 12 + h;
                    dst[(((size_t)bh * 2048 + tt) << 6) + feat] =
                        (bf16_t)((acc[i][j][r] + bv) * scale);
                }
            }
        }
    } else {
#pragma unroll
        for (int i = 0; i < 4; i++) {
            const int mbase = m0 + wm + i * 16 + quad * 4;
#pragma unroll
            for (int j = 0; j < NJ; j++) {
                const int n  = n0 + wn + j * 16 + l15;
                const float bv = bias[n];
#pragma unroll
                for (int r = 0; r < 4; r++)
                    ((float*)O0v)[(size_t)(mbase + r) * N + n] = acc[i][j][r] + bv;
            }
        }
    }
}

// ---------------------------------------------------------------------------
// Flash attention, causal — R13 form (frozen): 2-group body, LPT dispatch,
// XCD-bh L2 keying, 56KB LDS.  Measured 47.0us.  Five structural variants
// (R2/R3/R10/R11-12/R13) cluster at 47-52us ≈ 580 TF — structural plateau
// of this body; further gains need the full m214-style rewrite.
// ---------------------------------------------------------------------------
__global__ __launch_bounds__(256, 2) void attn_k(
    const bf16_t* __restrict__ Q, const bf16_t* __restrict__ Kb,
    const bf16_t* __restrict__ Vt, bf16_t* __restrict__ AO)
{
    __shared__ __align__(16) bf16_t Ks[2 * 4096];   // [buf][kk][kv64][feat32] swz
    __shared__ __align__(16) bf16_t Vs[2 * 4096];   // [buf][kk][feat64][kv32] swz
    __shared__ __align__(16) bf16_t Ps[4 * 3072];   // [wave][grp][16q][64kv] swz

    const int tid  = threadIdx.x;
    const int wid  = tid >> 6;
    const int lane = tid & 63;
    const int quad = lane >> 4;
    const int l15  = lane & 15;
    const int qs8  = (quad ^ ((l15 >> 1) & 3)) * 8;   // swizzled colblk

    const int bid = blockIdx.x;
    const int qt2 = 15 - (bid / 48);      // 128-row q-tile index, 15..0
    const int u   = bid % 48;
    const int bh  = (u & 7) * 6 + (u >> 3);
    const int q0  = qt2 << 7;

    const bf16_t* Qb  = Q  + ((size_t)bh << 17);
    const bf16_t* Kbh = Kb + ((size_t)bh << 17);
    const bf16_t* Vbh = Vt + ((size_t)bh << 17);

    bf16_t* Pw = Ps + wid * 3072;
    const int swl = l15 & 7;
    bf16_t* pwr[2][4];
    const bf16_t* prd[2][2];
#pragma unroll
    for (int g = 0; g < 2; g++) {
#pragma unroll
        for (int c = 0; c < 4; c++)
            pwr[g][c] = Pw + g * 1024 + l15 * 64 +
                        (((((c << 1) | (quad >> 1))) ^ swl) << 3) + ((quad & 1) << 2);
#pragma unroll
        for (int kk = 0; kk < 2; kk++)
            prd[g][kk] = Pw + g * 1024 + l15 * 64 + ((((kk << 2) | quad) ^ swl) << 3);
    }

    const bf16x8 ones = { (bf16_t)1.f, (bf16_t)1.f, (bf16_t)1.f, (bf16_t)1.f,
                          (bf16_t)1.f, (bf16_t)1.f, (bf16_t)1.f, (bf16_t)1.f };

    const int srow = tid >> 2;
    const int scol = (((tid & 3) ^ ((srow >> 1) & 3))) * 8;   // swizzled source col

    auto prefetch = [&](int j, int buf) {
        const int kv0 = j * 64;
        bf16_t* kd = Ks + buf * 4096 + tid * 8;
        bf16_t* vd = Vs + buf * 4096 + tid * 8;
#pragma unroll
        for (int c = 0; c < 2; c++) {
            gl_lds16(Kbh + (size_t)(kv0 + srow) * 64 + c * 32 + scol, kd + c * 2048);
            gl_lds16(Vbh + (size_t)srow * 2048 + kv0 + c * 32 + scol, vd + c * 2048);
        }
    };

    const int b = bh / 12;
    const int h = bh - b * 12;

    const int qg0 = q0 + wid * 16 + l15;   // group0 q-row
    const int qg1 = qg0 + 64;              // group1 q-row

    bf16x8 qf[2][2];
#pragma unroll
    for (int g = 0; g < 2; g++) {
        const bf16_t* qp = Qb + ((size_t)(g ? qg1 : qg0) << 6) + quad * 8;
        qf[g][0] = *(const bf16x8*)(qp);
        qf[g][1] = *(const bf16x8*)(qp + 32);
    }

    f32x4 lacc[2];
    f32x4 oacc[2][4];
#pragma unroll
    for (int g = 0; g < 2; g++) {
        lacc[g] = (f32x4){0.f, 0.f, 0.f, 0.f};
#pragma unroll
        for (int f = 0; f < 4; f++) oacc[g][f] = (f32x4){0.f, 0.f, 0.f, 0.f};
    }

    const int cnt = 2 * qt2 + 2;           // kv tiles needed by group1
    prefetch(0, 0);

    for (int i = 0; i < cnt; i++) {
        __syncthreads();                   // drains prefetch from iter i-1
        if (i + 1 < cnt) prefetch(i + 1, (i + 1) & 1);
        const bf16_t* Kp = Ks + (i & 1) * 4096;
        const bf16_t* Vp = Vs + (i & 1) * 4096;

        // S^T = K Q^T for both q-groups: kf loaded ONCE, used twice.
        f32x4 st[2][4];
        __builtin_amdgcn_s_setprio(1);
#pragma unroll
        for (int c = 0; c < 4; c++) {
            st[0][c] = (f32x4){0.f, 0.f, 0.f, 0.f};
            st[1][c] = (f32x4){0.f, 0.f, 0.f, 0.f};
#pragma unroll
            for (int kk = 0; kk < 2; kk++) {
                bf16x8 kf = *(const bf16x8*)(Kp + kk * 2048 + (c * 16 + l15) * 32 + qs8);
                st[0][c] = MFMA16(kf, qf[0][kk], st[0][c]);
                st[1][c] = MFMA16(kf, qf[1][kk], st[1][c]);
            }
        }
        __builtin_amdgcn_s_setprio(0);

        // Causal masks.  Group0 diag at i==2*qt2; fully masked at i==2*qt2+1
        // (exp -> 0, branch-free).  Group1 diag at i==2*qt2+1.
        const int kvb = i * 64 + quad * 4;
        if (i >= 2 * qt2) {
#pragma unroll
            for (int c = 0; c < 4; c++)
#pragma unroll
                for (int r = 0; r < 4; r++)
                    if (kvb + c * 16 + r > qg0) st[0][c][r] = -3e38f;
            if (i == 2 * qt2 + 1) {
#pragma unroll
                for (int c = 0; c < 4; c++)
#pragma unroll
                    for (int r = 0; r < 4; r++)
                        if (kvb + c * 16 + r > qg1) st[1][c][r] = -3e38f;
            }
        }

        // P^T = exp2(S^T): one b64 LDS write per (g,c)
#pragma unroll
        for (int g = 0; g < 2; g++)
#pragma unroll
            for (int c = 0; c < 4; c++) {
                bf16x4 pk = { (bf16_t)fexp2(st[g][c][0]), (bf16_t)fexp2(st[g][c][1]),
                              (bf16_t)fexp2(st[g][c][2]), (bf16_t)fexp2(st[g][c][3]) };
                *(bf16x4*)pwr[g][c] = pk;
            }

        bf16x8 pb[2][2];
#pragma unroll
        for (int g = 0; g < 2; g++)
#pragma unroll
            for (int kk = 0; kk < 2; kk++)
                pb[g][kk] = *(const bf16x8*)prd[g][kk];

        __builtin_amdgcn_s_setprio(1);
        // l[q] += colsum(P^T): lands at col=l15 (lane-local)
        lacc[0] = MFMA16(ones, pb[0][0], lacc[0]);
        lacc[0] = MFMA16(ones, pb[0][1], lacc[0]);
        lacc[1] = MFMA16(ones, pb[1][0], lacc[1]);
        lacc[1] = MFMA16(ones, pb[1][1], lacc[1]);

        // O^T += V^T P^T for both groups: vf loaded ONCE, used twice.
#pragma unroll
        for (int f = 0; f < 4; f++)
#pragma unroll
            for (int kk = 0; kk < 2; kk++) {
                bf16x8 vf = *(const bf16x8*)(Vp + kk * 2048 + (f * 16 + l15) * 32 + qs8);
                oacc[0][f] = MFMA16(vf, pb[0][kk], oacc[0][f]);
                oacc[1][f] = MFMA16(vf, pb[1][kk], oacc[1][f]);
            }
        __builtin_amdgcn_s_setprio(0);
    }

    // Epilogue: normalize in-register (l lane-local) -> bf16 AO, both groups
#pragma unroll
    for (int g = 0; g < 2; g++) {
        const float inv = 1.0f / lacc[g][0];
        const int qg = g ? qg1 : qg0;
        bf16_t* dst = AO + ((size_t)(b * 2048 + qg)) * 768 + h * 64 + quad * 4;
#pragma unroll
        for (int f = 0; f < 4; f++) {
            bf16x4 o = { (bf16_t)(oacc[g][f][0] * inv), (bf16_t)(oacc[g][f][1] * inv),
                         (bf16_t)(oacc[g][f][2] * inv), (bf16_t)(oacc[g][f][3] * inv) };
            *(bf16x4*)(dst + f * 16) = o;
        }
    }
}

// ---------------------------------------------------------------------------
extern "C" void kernel_launch(void* const* d_in, const int* in_sizes, int n_in,
                              void* d_out, int out_size, void* d_ws, size_t ws_size,
                              hipStream_t stream)
{
    const float* x    = (const float*)d_in[0];  // [4,2048,768]
    const float* Wqkv = (const float*)d_in[1];  // [768,2304]
    const float* bqkv = (const float*)d_in[2];  // [2304]
    const float* Wo   = (const float*)d_in[3];  // [768,768]
    const float* bo   = (const float*)d_in[4];  // [768]
    float* out = (float*)d_out;                 // [4,2048,768] fp32

    const size_t per = (size_t)48 * 2048 * 64;  // 6291456 bf16 elems
    bf16_t* Qs  = (bf16_t*)d_ws;                // [bh][t][64], pre-scaled
    bf16_t* Kk  = Qs + per;                     // [bh][t][64]
    bf16_t* Vt  = Kk + per;                     // [bh][64][t]
    bf16_t* AO  = Vt + per;                     // [8192,768] bf16
    bf16_t* xb  = AO + per;                     // [8192,768] bf16
    bf16_t* Wt  = xb + per;                     // [2304,768] = Wqkv^T bf16
    bf16_t* Wot = Wt + (size_t)2304 * 768;      // [768,768]  = Wo^T bf16
    bf16_t* Vpl = (bf16_t*)d_out;               // V plain parked in out

    // 0) merged precision/layout conversions
    prep_k<<<8448, 256, 0, stream>>>(x, xb, Wqkv, Wt, Wo, Wot);

    // 1) QKV projection (coalesced [bh][t][64] for Q, K, V-plain)
    gemm_bt<0, 128><<<18 * 64, 256, 0, stream>>>(
        xb, Wt, bqkv, (void*)Qs, Kk, Vpl, 8192, 2304, 768);
    // 1b) V transpose -> Vt [bh][64][t]
    vtrans<<<dim3(32, 48), 256, 0, stream>>>(Vpl, Vt);
    // 2) causal flash attention -> normalized AO (bf16)
    attn_k<<<768, 256, 0, stream>>>(Qs, Kk, Vt, AO);
    // 3) output projection (fp32 out), 128x64 tiles -> 768 blocks = 3/CU exact
    gemm_bt<1, 64><<<12 * 64, 256, 0, stream>>>(
        AO, Wot, bo, (void*)out, nullptr, nullptr, 8192, 768, 768);
}